// Round 11
// baseline (420.913 us; speedup 1.0000x reference)
//
#include <hip/hip_runtime.h>
#include <hip/hip_bf16.h>

// AgreementRouting, single NORMAL-launch kernel, register-resident u.
// B=128, IC=1152, OC=10, D=16, 3 iters, f32 in/out.
//
// 512 blocks x 256 thr, __launch_bounds__(256,2): guide-sanctioned capacity
// guarantee (k=2 wg/CU, grid 512 = 2x256 -> all blocks co-resident; VGPR cap
// 256 >> ~150 live, LDS 15KB << 80KB). NO hipLaunchCooperativeKernel (R4/R10:
// silent launch rejection with big register arrays; R3 proved the agent-scope
// data-exchange pattern itself is sound).
//
// 4 parts per b (part=bid&3), each owns 288 slices. u read from HBM EXACTLY
// ONCE (P0, f32, coalesced 184KB/block), kept as bf16 in 90 VGPRs/thread
// (uw[18*5], static indexing only). Phases 1..3: pure VALU from registers.
// Logits: bb_T = b_in + <u, sum_{t<T} v_t> (linearity, R2-proven).
//
// Per-b sync: tag barrier. slot[b][part] gets phase-unique tag TAGP(T)
// (0x51C0000T) via release-store; waiters equality-poll all 4 slots.
// Entry garbage (0xAA poison / stale TAG4 from prev call) never equals an
// awaited tag -> no init kernel, deterministic under graph replay.
// s_part[t] buffers are distinct per phase -> no reuse hazards.
//
// Lane scheme per 16-lane group (slice = 10x16 f32): l=tid&15, h=l>>3.
// Lane owns (j=2k+h, d=2(l&7)..2(l&7)+1), k=0..4 == float offset 32k+2l.
// Cross-lane in hot loops: all DPP (VALU pipe), R6-proven.

#define B_     128
#define IC_    1152
#define OC_    10
#define ROW_   160
#define PARTS_ 4
#define SPB_   288     // slices per part
#define UPB_   18      // slices per 16-lane group
#define GSTR_  64      // dwords per b's slot array (4 slots x 16 dwords)
#define TAGP(p) (0x51C00000u + (uint32_t)(p))

typedef float v2f __attribute__((ext_vector_type(2)));

__device__ __forceinline__ float bf_lo(uint32_t w) { return __uint_as_float(w << 16); }
__device__ __forceinline__ float bf_hi(uint32_t w) { return __uint_as_float(w & 0xffff0000u); }

template<int CTRL>
__device__ __forceinline__ float dppf(float x) {
    return __int_as_float(__builtin_amdgcn_update_dpp(
        0, __float_as_int(x), CTRL, 0xF, 0xF, true));
}
__device__ __forceinline__ float dpp_sum8(float x) {
    x += dppf<0xB1>(x);    // quad_perm [1,0,3,2]  (xor1)
    x += dppf<0x4E>(x);    // quad_perm [2,3,0,1]  (xor2)
    x += dppf<0x141>(x);   // row_half_mirror      (cross-quad within 8)
    return x;
}
__device__ __forceinline__ float softmax10(float own[5]) {
    float m = own[0];
#pragma unroll
    for (int k = 1; k < 5; ++k) m = fmaxf(m, own[k]);
    m = fmaxf(m, dppf<0x128>(m));          // row_ror:8 == xor8 within 16
    float sum = 0.f;
#pragma unroll
    for (int k = 0; k < 5; ++k) { own[k] = __expf(own[k] - m); sum += own[k]; }
    sum += dppf<0x128>(sum);
    return 1.f / sum;
}

__device__ __forceinline__ float agent_loadf(const float* p) {
    return __hip_atomic_load(p, __ATOMIC_RELAXED, __HIP_MEMORY_SCOPE_AGENT);
}
__device__ __forceinline__ void agent_storef(float* p, float v) {
    __hip_atomic_store(p, v, __ATOMIC_RELAXED, __HIP_MEMORY_SCOPE_AGENT);
}

__device__ __forceinline__ void gbar(uint32_t* gslots, int tid, int part, uint32_t tag) {
    __threadfence();
    __syncthreads();            // all block stores complete & fenced
    if (tid == 0)
        __hip_atomic_store(&gslots[part * 16], tag, __ATOMIC_RELEASE, __HIP_MEMORY_SCOPE_AGENT);
    if (tid < PARTS_)
        while (__hip_atomic_load(&gslots[tid * 16], __ATOMIC_ACQUIRE, __HIP_MEMORY_SCOPE_AGENT) != tag)
            __builtin_amdgcn_s_sleep(2);
    __syncthreads();
}

__global__ __launch_bounds__(256, 2) void routing_kernel(
    const float* __restrict__ u, const float* __restrict__ b_in,
    uint32_t* __restrict__ slots, float* __restrict__ s_part,
    float* __restrict__ out)
{
    const int bid = blockIdx.x, tid = threadIdx.x;
    const int l = tid & 15, h = l >> 3, g = tid >> 4;
    const int b = bid >> 2, part = bid & 3;
    const int wave = tid >> 6, lane = tid & 63;
    uint32_t* gslots = slots + b * GSTR_;

    __shared__ float red[4][ROW_];
    __shared__ float v_lds[ROW_];
    __shared__ float b_lds[SPB_ * OC_];   // 11.5 KB, this part's b_in rows

    // stage this part's b_in rows (2880 contiguous floats)
#pragma unroll
    for (int it = 0; it < 12; ++it) {
        int idx = it * 256 + tid;
        if (idx < SPB_ * OC_) b_lds[idx] = b_in[part * SPB_ * OC_ + idx];
    }
    __syncthreads();

    uint32_t uw[UPB_ * 5];     // bf16 u, register-resident (static indexing)

    // ---------------- P0: f32 u -> s0 partial; stash bf16 ----------------
    {
        float2 sc[5];
#pragma unroll
        for (int k = 0; k < 5; ++k) { sc[k].x = 0.f; sc[k].y = 0.f; }
#pragma unroll
        for (int uu = 0; uu < UPB_; ++uu) {
            const int su = uu * 16 + g;
            const int i  = part * SPB_ + su;
            const v2f* up = (const v2f*)(u + (size_t)(b * IC_ + i) * ROW_ + 2 * l);
            v2f uv[5];
#pragma unroll
            for (int k = 0; k < 5; ++k) uv[k] = __builtin_nontemporal_load(up + 16 * k);
#pragma unroll
            for (int k = 0; k < 5; ++k) {
                __hip_bfloat16 bx = __float2bfloat16(uv[k].x);
                __hip_bfloat16 by = __float2bfloat16(uv[k].y);
                uw[uu * 5 + k] = ((uint32_t)(*(const uint16_t*)&by) << 16) |
                                  (uint32_t)(*(const uint16_t*)&bx);
            }
            float own[5];
#pragma unroll
            for (int k = 0; k < 5; ++k) own[k] = b_lds[su * OC_ + 2 * k + h];
            const float inv = softmax10(own);
#pragma unroll
            for (int k = 0; k < 5; ++k) {
                float c = own[k] * inv;
                sc[k].x += c * uv[k].x; sc[k].y += c * uv[k].y;
            }
        }
#pragma unroll
        for (int k = 0; k < 5; ++k) {
            sc[k].x += __shfl_xor(sc[k].x, 16); sc[k].y += __shfl_xor(sc[k].y, 16);
            sc[k].x += __shfl_xor(sc[k].x, 32); sc[k].y += __shfl_xor(sc[k].y, 32);
        }
        if (lane < 16) {
#pragma unroll
            for (int k = 0; k < 5; ++k)
                *(float2*)&red[wave][32 * k + 2 * l] = sc[k];
        }
        __syncthreads();
        if (tid < ROW_) {
            float t = red[0][tid] + red[1][tid] + red[2][tid] + red[3][tid];
            agent_storef(&s_part[((size_t)(0 * B_ + b) * PARTS_ + part) * ROW_ + tid], t);
        }
        gbar(gslots, tid, part, TAGP(1));
    }

    // ---------------- phases 1..3 (pure registers) ----------------
    float vsum = 0.f;          // valid for tid<ROW_
    for (int T = 1; T <= 3; ++T) {
        if (tid < ROW_) {
            const float* sp = s_part + ((size_t)((T - 1) * B_ + b) * PARTS_) * ROW_;
            float x = 0.f;
#pragma unroll
            for (int p = 0; p < PARTS_; ++p) x += agent_loadf(sp + p * ROW_ + tid);
            float sq = x * x;
            sq += __shfl_xor(sq, 1, 16);
            sq += __shfl_xor(sq, 2, 16);
            sq += __shfl_xor(sq, 4, 16);
            sq += __shfl_xor(sq, 8, 16);
            vsum += (sq / (1.f + sq)) * x * rsqrtf(sq + 1e-8f);
            v_lds[tid] = vsum;
        }
        __syncthreads();

        float2 vv[5];
#pragma unroll
        for (int k = 0; k < 5; ++k)
            vv[k] = *(const float2*)&v_lds[32 * k + 2 * l];

        float2 sc[5];
#pragma unroll
        for (int k = 0; k < 5; ++k) { sc[k].x = 0.f; sc[k].y = 0.f; }
#pragma unroll
        for (int uu = 0; uu < UPB_; ++uu) {
            const int su = uu * 16 + g;
            float own[5];
#pragma unroll
            for (int k = 0; k < 5; ++k) {
                uint32_t w = uw[uu * 5 + k];
                float pd = bf_lo(w) * vv[k].x + bf_hi(w) * vv[k].y;
                own[k] = b_lds[su * OC_ + 2 * k + h] + dpp_sum8(pd);
            }
            const float inv = softmax10(own);
#pragma unroll
            for (int k = 0; k < 5; ++k) {
                float c = own[k] * inv;
                uint32_t w = uw[uu * 5 + k];
                sc[k].x += c * bf_lo(w); sc[k].y += c * bf_hi(w);
            }
        }
#pragma unroll
        for (int k = 0; k < 5; ++k) {
            sc[k].x += __shfl_xor(sc[k].x, 16); sc[k].y += __shfl_xor(sc[k].y, 16);
            sc[k].x += __shfl_xor(sc[k].x, 32); sc[k].y += __shfl_xor(sc[k].y, 32);
        }
        if (lane < 16) {
#pragma unroll
            for (int k = 0; k < 5; ++k)
                *(float2*)&red[wave][32 * k + 2 * l] = sc[k];
        }
        __syncthreads();
        if (tid < ROW_) {
            float t = red[0][tid] + red[1][tid] + red[2][tid] + red[3][tid];
            agent_storef(&s_part[((size_t)(T * B_ + b) * PARTS_ + part) * ROW_ + tid], t);
        }

        if (T < 3) {
            gbar(gslots, tid, part, TAGP(T + 1));
        } else {
            // final: all arrive; part 0 waits, reduces, squashes, writes out
            __threadfence();
            __syncthreads();
            if (tid == 0)
                __hip_atomic_store(&gslots[part * 16], TAGP(4),
                                   __ATOMIC_RELEASE, __HIP_MEMORY_SCOPE_AGENT);
            if (part == 0) {
                if (tid < PARTS_)
                    while (__hip_atomic_load(&gslots[tid * 16], __ATOMIC_ACQUIRE,
                                             __HIP_MEMORY_SCOPE_AGENT) != TAGP(4))
                        __builtin_amdgcn_s_sleep(2);
                __syncthreads();
                if (tid < ROW_) {
                    const float* sp = s_part + ((size_t)(3 * B_ + b) * PARTS_) * ROW_;
                    float x = 0.f;
#pragma unroll
                    for (int p = 0; p < PARTS_; ++p) x += agent_loadf(sp + p * ROW_ + tid);
                    float sq = x * x;
                    sq += __shfl_xor(sq, 1, 16);
                    sq += __shfl_xor(sq, 2, 16);
                    sq += __shfl_xor(sq, 4, 16);
                    sq += __shfl_xor(sq, 8, 16);
                    out[b * ROW_ + tid] = (sq / (1.f + sq)) * x * rsqrtf(sq + 1e-8f);
                }
            }
        }
    }
}

extern "C" void kernel_launch(void* const* d_in, const int* in_sizes, int n_in,
                              void* d_out, int out_size, void* d_ws, size_t ws_size,
                              hipStream_t stream) {
    const float* u    = (const float*)d_in[0];
    const float* b_in = (const float*)d_in[1];
    float* out = (float*)d_out;

    uint32_t* slots  = (uint32_t*)d_ws;                    // 128*64 dwords = 32 KB
    float*    s_part = (float*)(slots + B_ * GSTR_);       // 4*128*4*160 f32 = 1.31 MB

    routing_kernel<<<dim3(B_ * PARTS_), dim3(256), 0, stream>>>(
        u, b_in, slots, s_part, out);
}